// Round 1
// baseline (9004.095 us; speedup 1.0000x reference)
//
#include <hip/hip_runtime.h>
#include <cstdint>
#include <cstddef>

// LSTM_Generator: 3-layer LSTM (H=100) + tanh projection.
// B=512, T=512. fp32 throughout (accuracy threshold forbids bf16).
//
// Strategy: one block per batch element (512 blocks, 512 threads).
// Threads 0..399 own gate row r, weights in registers (Whh row + Wih row).
// h broadcast via LDS (uniform ds_read_b128 = free broadcast).
// Input matvec fused into the recurrence (no xw precompute / storage).
// In-place h-sequence buffer in d_ws (52.4 MB).

#define HH 100   // hidden
#define G4 400   // 4*H
#define NB 512   // batch
#define NT 512   // timesteps

__device__ __forceinline__ float fast_sigmoid(float x) {
  return 1.0f / (1.0f + __expf(-x));
}
// tanh(x) = 1 - 2/(exp(2x)+1): stable at both infinities, ~1e-7 abs error.
__device__ __forceinline__ float fast_tanh(float x) {
  return 1.0f - 2.0f / (__expf(2.0f * x) + 1.0f);
}

template <int INPUT_K>
__global__ __launch_bounds__(512, 2) void lstm_layer_kernel(
    const float* x,                   // [NB, NT, INPUT_K]  (NOT restrict: may alias hseq, in-place)
    const float* __restrict__ Wih,    // [G4, INPUT_K]
    const float* __restrict__ Whh,    // [G4, HH]
    const float* __restrict__ bias,   // [G4]
    float* hseq)                      // [NB, NT, HH] output (may alias x)
{
  const int b = blockIdx.x;
  const int r = threadIdx.x;

  __shared__ __align__(16) float h_lds[HH];
  __shared__ __align__(16) float gates[G4];

  float wih[INPUT_K];
  float whh[HH];
  float bb = 0.0f;

  if (r < G4) {
    const float4* w4 = reinterpret_cast<const float4*>(Whh + r * HH);
#pragma unroll
    for (int k = 0; k < HH / 4; ++k) {
      float4 v = w4[k];
      whh[4 * k] = v.x; whh[4 * k + 1] = v.y; whh[4 * k + 2] = v.z; whh[4 * k + 3] = v.w;
    }
    if constexpr (INPUT_K == 1) {
      wih[0] = Wih[r];
    } else {
      const float4* wi4 = reinterpret_cast<const float4*>(Wih + r * INPUT_K);
#pragma unroll
      for (int k = 0; k < INPUT_K / 4; ++k) {
        float4 v = wi4[k];
        wih[4 * k] = v.x; wih[4 * k + 1] = v.y; wih[4 * k + 2] = v.z; wih[4 * k + 3] = v.w;
      }
    }
    bb = bias[r];
  }

  if (r < HH) h_lds[r] = 0.0f;
  float c = 0.0f;  // cell state for row r < HH, private register

  const float* xb = x + (size_t)b * NT * INPUT_K;
  float* hb = hseq + (size_t)b * NT * HH;

  __syncthreads();

  for (int t = 0; t < NT; ++t) {
    if (r < G4) {
      float a0 = 0.f, a1 = 0.f, a2 = 0.f, a3 = 0.f;
      if constexpr (INPUT_K != 1) {
        // input contribution: x_t is wave-uniform (broadcast load, L1/L3)
        const float4* x4 = reinterpret_cast<const float4*>(xb + (size_t)t * INPUT_K);
#pragma unroll
        for (int k = 0; k < INPUT_K / 4; ++k) {
          float4 xv = x4[k];
          a0 += xv.x * wih[4 * k];
          a1 += xv.y * wih[4 * k + 1];
          a2 += xv.z * wih[4 * k + 2];
          a3 += xv.w * wih[4 * k + 3];
        }
      }
      // recurrent contribution: h from LDS, uniform address -> broadcast
      const float4* h4 = reinterpret_cast<const float4*>(h_lds);
#pragma unroll
      for (int k = 0; k < HH / 4; ++k) {
        float4 hv = h4[k];
        a0 += hv.x * whh[4 * k];
        a1 += hv.y * whh[4 * k + 1];
        a2 += hv.z * whh[4 * k + 2];
        a3 += hv.w * whh[4 * k + 3];
      }
      float acc = bb + ((a0 + a1) + (a2 + a3));
      if constexpr (INPUT_K == 1) acc += xb[t] * wih[0];
      gates[r] = acc;
    }
    __syncthreads();
    if (r < HH) {
      float gi = gates[r];
      float gf = gates[r + HH];
      float gg = gates[r + 2 * HH];
      float go = gates[r + 3 * HH];
      float iv = fast_sigmoid(gi);
      float fv = fast_sigmoid(gf);
      float gv = fast_tanh(gg);
      float ov = fast_sigmoid(go);
      c = fv * c + iv * gv;
      float hv = ov * fast_tanh(c);
      h_lds[r] = hv;
      hb[(size_t)t * HH + r] = hv;   // 100 contiguous floats per block/step
    }
    __syncthreads();
  }
}

__global__ __launch_bounds__(256) void proj_kernel(
    const float* __restrict__ hseq,  // [NB*NT, HH]
    const float* __restrict__ Wp,    // [1, HH]
    const float* __restrict__ bp,    // [1]
    float* __restrict__ out)         // [NB*NT]
{
  int idx = blockIdx.x * blockDim.x + threadIdx.x;
  if (idx >= NB * NT) return;
  const float4* h4 = reinterpret_cast<const float4*>(hseq + (size_t)idx * HH);
  const float4* w4 = reinterpret_cast<const float4*>(Wp);
  float a0 = 0.f, a1 = 0.f, a2 = 0.f, a3 = 0.f;
#pragma unroll
  for (int k = 0; k < HH / 4; ++k) {
    float4 h = h4[k];
    float4 w = w4[k];
    a0 += h.x * w.x; a1 += h.y * w.y; a2 += h.z * w.z; a3 += h.w * w.w;
  }
  out[idx] = fast_tanh(((a0 + a1) + (a2 + a3)) + bp[0]);
}

extern "C" void kernel_launch(void* const* d_in, const int* in_sizes, int n_in,
                              void* d_out, int out_size, void* d_ws, size_t ws_size,
                              hipStream_t stream) {
  const float* z    = (const float*)d_in[0];
  const float* Wih0 = (const float*)d_in[1];
  const float* Whh0 = (const float*)d_in[2];
  const float* b0   = (const float*)d_in[3];
  const float* Wih1 = (const float*)d_in[4];
  const float* Whh1 = (const float*)d_in[5];
  const float* b1   = (const float*)d_in[6];
  const float* Wih2 = (const float*)d_in[7];
  const float* Whh2 = (const float*)d_in[8];
  const float* b2   = (const float*)d_in[9];
  const float* Wp   = (const float*)d_in[10];
  const float* bp   = (const float*)d_in[11];
  float* out = (float*)d_out;

  // single in-place h-sequence buffer: [NB, NT, HH] fp32 = 52.4 MB
  float* hbuf = (float*)d_ws;

  dim3 grid(NB), block(512);
  // layer 0: input z [B,T,1], K=1
  lstm_layer_kernel<1><<<grid, block, 0, stream>>>(z, Wih0, Whh0, b0, hbuf);
  // layers 1,2: fused input matvec, in-place on hbuf
  lstm_layer_kernel<HH><<<grid, block, 0, stream>>>(hbuf, Wih1, Whh1, b1, hbuf);
  lstm_layer_kernel<HH><<<grid, block, 0, stream>>>(hbuf, Wih2, Whh2, b2, hbuf);
  // projection: [B*T] outputs
  proj_kernel<<<(NB * NT + 255) / 256, 256, 0, stream>>>(hbuf, Wp, bp, out);
}

// Round 2
// 3499.176 us; speedup vs baseline: 2.5732x; 2.5732x over previous
//
#include <hip/hip_runtime.h>
#include <cstdint>
#include <cstddef>

// LSTM_Generator: 3-layer LSTM (H=100) + tanh projection. B=512, T=512, fp32.
//
// R1 redesign: eliminate register spill (R0: wih[100]+whh[100]=200 regs vs 128 cap)
// by wave-specialized groups in a 1024-thread block, each thread holding exactly
// ONE weight row in a SINGLE unified w[100] array:
//   HG (tid 0..399):    Whh row (unit-major quad map r=4u+g), computes gates(t)
//   XG (tid 512..911):  Wih row + bias, computes xacc(t+1) one step AHEAD
//   PF (tid 912..1011): prefetch x(t+2) global->LDS double buffer
// One barrier per step; gate exchange via ds_swizzle quad-broadcast (no gates[]
// staging, no second barrier); h double-buffered in LDS.

#define HH 100   // hidden
#define G4 400   // 4*H
#define NB 512   // batch
#define NT 512   // timesteps

__device__ __forceinline__ float sigm(float x) {
  return 1.0f / (1.0f + __expf(-x));
}
__device__ __forceinline__ float tanh_(float x) {
  return 1.0f - 2.0f / (__expf(2.0f * x) + 1.0f);
}
// quad broadcasts: all 4 lanes of a quad get lane k's value (QDMode swizzle)
__device__ __forceinline__ float qb1(float v) {
  return __int_as_float(__builtin_amdgcn_ds_swizzle(__float_as_int(v), 0x8055));
}
__device__ __forceinline__ float qb2(float v) {
  return __int_as_float(__builtin_amdgcn_ds_swizzle(__float_as_int(v), 0x80AA));
}
__device__ __forceinline__ float qb3(float v) {
  return __int_as_float(__builtin_amdgcn_ds_swizzle(__float_as_int(v), 0x80FF));
}

// -------- layers 1,2: K=100, fused pipelined input matvec --------
__global__ __launch_bounds__(1024, 1) void lstm_pipe100(
    const float* x,                   // [NB, NT, HH]   (aliases hseq: in-place)
    const float* __restrict__ Wih,    // [G4, HH]
    const float* __restrict__ Whh,    // [G4, HH]
    const float* __restrict__ bias,   // [G4]
    float* hseq)                      // [NB, NT, HH]
{
  const int b = blockIdx.x;
  const int tid = threadIdx.x;

  __shared__ __align__(16) float h_dbuf[2][HH];
  __shared__ __align__(16) float xacc[2][G4];
  __shared__ __align__(16) float x_lds[2][HH];

  const bool isHG = tid < G4;
  const bool isXG = (tid >= 512) && (tid < 512 + G4);
  const int r = isHG ? tid : (tid - 512);     // row slot 0..399
  const int u = r >> 2;                       // hidden unit
  const int g = r & 3;                        // gate: 0=i,1=f,2=g,3=o
  const int row = g * HH + u;                 // row in [4H, H] weight layout

  float w[HH];                                // ONE row: Whh (HG) or Wih (XG)
  float bb = 0.0f;
  if (isHG || isXG) {
    const float* wsrc = isHG ? (Whh + (size_t)row * HH) : (Wih + (size_t)row * HH);
    const float4* w4 = reinterpret_cast<const float4*>(wsrc);
#pragma unroll
    for (int k = 0; k < HH / 4; ++k) {
      float4 v = w4[k];
      w[4 * k] = v.x; w[4 * k + 1] = v.y; w[4 * k + 2] = v.z; w[4 * k + 3] = v.w;
    }
    if (isXG) bb = bias[row];
  }
  if (tid < HH) h_dbuf[0][tid] = 0.0f;
  float c = 0.0f;

  const float* xb = x + (size_t)b * NT * HH;
  float* hb = hseq + (size_t)b * NT * HH;

  // PF preload x(0), x(1)
  const int pf = tid - 912;                   // 0..111; active if < HH
  if (pf >= 0 && pf < HH) {
    x_lds[0][pf] = xb[pf];
    x_lds[1][pf] = xb[HH + pf];
  }
  __syncthreads();

  // prologue: xacc(0) from x_lds[0]
  if (isXG) {
    float a0 = 0.f, a1 = 0.f;
    const float4* s4 = reinterpret_cast<const float4*>(x_lds[0]);
#pragma unroll
    for (int k = 0; k < HH / 4; ++k) {
      float4 v = s4[k];
      a0 += v.x * w[4 * k] + v.y * w[4 * k + 1];
      a1 += v.z * w[4 * k + 2] + v.w * w[4 * k + 3];
    }
    xacc[0][r] = bb + a0 + a1;
  }
  __syncthreads();

  for (int t = 0; t < NT; ++t) {
    const int cur = t & 1, nxt = cur ^ 1;

    // PF: x(t+2) -> x_lds[cur]  (consumed by XG at step t+1 as buffer (t+1)^1... = cur)
    if (pf >= 0 && pf < HH) {
      int tt = (t + 2 < NT) ? (t + 2) : (NT - 1);
      x_lds[cur][pf] = xb[(size_t)tt * HH + pf];
    }

    // XG: xacc(t+1) = b + Wih . x(t+1), from x_lds[nxt]
    if (isXG) {
      float a0 = 0.f, a1 = 0.f;
      const float4* s4 = reinterpret_cast<const float4*>(x_lds[nxt]);
#pragma unroll
      for (int k = 0; k < HH / 4; ++k) {
        float4 v = s4[k];
        a0 += v.x * w[4 * k] + v.y * w[4 * k + 1];
        a1 += v.z * w[4 * k + 2] + v.w * w[4 * k + 3];
      }
      xacc[nxt][r] = bb + a0 + a1;
    }

    // HG: gates(t) = xacc(t) + Whh . h(t-1); activation; quad-gather; update
    if (isHG) {
      float xa = xacc[cur][r];
      float a0 = 0.f, a1 = 0.f;
      const float4* s4 = reinterpret_cast<const float4*>(h_dbuf[cur]);
#pragma unroll
      for (int k = 0; k < HH / 4; ++k) {
        float4 v = s4[k];
        a0 += v.x * w[4 * k] + v.y * w[4 * k + 1];
        a1 += v.z * w[4 * k + 2] + v.w * w[4 * k + 3];
      }
      float acc = xa + a0 + a1;
      float act = (g == 2) ? tanh_(acc) : sigm(acc);
      float fv = qb1(act);
      float gv = qb2(act);
      float ov = qb3(act);
      if (g == 0) {                           // lane 4u: owns c,h of unit u
        c = fv * c + act * gv;
        float hv = ov * tanh_(c);
        h_dbuf[nxt][u] = hv;
        hb[(size_t)t * HH + u] = hv;
      }
    }
    __syncthreads();
  }
}

// -------- layer 0: K=1 (scalar input), 512 threads, 2 blocks/CU --------
__global__ __launch_bounds__(512, 2) void lstm_pipe1(
    const float* __restrict__ z,      // [NB, NT, 1]
    const float* __restrict__ Wih,    // [G4, 1]
    const float* __restrict__ Whh,    // [G4, HH]
    const float* __restrict__ bias,   // [G4]
    float* __restrict__ hseq)         // [NB, NT, HH]
{
  const int b = blockIdx.x;
  const int tid = threadIdx.x;

  __shared__ __align__(16) float h_dbuf[2][HH];

  const bool isHG = tid < G4;
  const int u = tid >> 2, g = tid & 3;
  const int row = g * HH + u;

  float w[HH];
  float w0 = 0.f, bb = 0.f, c = 0.f;
  if (isHG) {
    const float4* w4 = reinterpret_cast<const float4*>(Whh + (size_t)row * HH);
#pragma unroll
    for (int k = 0; k < HH / 4; ++k) {
      float4 v = w4[k];
      w[4 * k] = v.x; w[4 * k + 1] = v.y; w[4 * k + 2] = v.z; w[4 * k + 3] = v.w;
    }
    w0 = Wih[row];
    bb = bias[row];
  }
  if (tid < HH) h_dbuf[0][tid] = 0.0f;

  const float* zb = z + (size_t)b * NT;
  float* hb = hseq + (size_t)b * NT * HH;

  float zc = zb[0];                           // register-rotated z prefetch
  __syncthreads();

  for (int t = 0; t < NT; ++t) {
    const int cur = t & 1, nxt = cur ^ 1;
    float zn = (t + 1 < NT) ? zb[t + 1] : 0.f;  // issue early, consume next iter

    if (isHG) {
      float a0 = 0.f, a1 = 0.f;
      const float4* s4 = reinterpret_cast<const float4*>(h_dbuf[cur]);
#pragma unroll
      for (int k = 0; k < HH / 4; ++k) {
        float4 v = s4[k];
        a0 += v.x * w[4 * k] + v.y * w[4 * k + 1];
        a1 += v.z * w[4 * k + 2] + v.w * w[4 * k + 3];
      }
      float acc = bb + w0 * zc + a0 + a1;
      float act = (g == 2) ? tanh_(acc) : sigm(acc);
      float fv = qb1(act);
      float gv = qb2(act);
      float ov = qb3(act);
      if (g == 0) {
        c = fv * c + act * gv;
        float hv = ov * tanh_(c);
        h_dbuf[nxt][u] = hv;
        hb[(size_t)t * HH + u] = hv;
      }
    }
    zc = zn;
    __syncthreads();
  }
}

// -------- projection --------
__global__ __launch_bounds__(256) void proj_kernel(
    const float* __restrict__ hseq,  // [NB*NT, HH]
    const float* __restrict__ Wp,    // [1, HH]
    const float* __restrict__ bp,    // [1]
    float* __restrict__ out)         // [NB*NT]
{
  int idx = blockIdx.x * blockDim.x + threadIdx.x;
  if (idx >= NB * NT) return;
  const float4* h4 = reinterpret_cast<const float4*>(hseq + (size_t)idx * HH);
  const float4* w4 = reinterpret_cast<const float4*>(Wp);
  float a0 = 0.f, a1 = 0.f, a2 = 0.f, a3 = 0.f;
#pragma unroll
  for (int k = 0; k < HH / 4; ++k) {
    float4 h = h4[k];
    float4 w = w4[k];
    a0 += h.x * w.x; a1 += h.y * w.y; a2 += h.z * w.z; a3 += h.w * w.w;
  }
  out[idx] = tanh_(((a0 + a1) + (a2 + a3)) + bp[0]);
}

extern "C" void kernel_launch(void* const* d_in, const int* in_sizes, int n_in,
                              void* d_out, int out_size, void* d_ws, size_t ws_size,
                              hipStream_t stream) {
  const float* z    = (const float*)d_in[0];
  const float* Wih0 = (const float*)d_in[1];
  const float* Whh0 = (const float*)d_in[2];
  const float* b0   = (const float*)d_in[3];
  const float* Wih1 = (const float*)d_in[4];
  const float* Whh1 = (const float*)d_in[5];
  const float* b1   = (const float*)d_in[6];
  const float* Wih2 = (const float*)d_in[7];
  const float* Whh2 = (const float*)d_in[8];
  const float* b2   = (const float*)d_in[9];
  const float* Wp   = (const float*)d_in[10];
  const float* bp   = (const float*)d_in[11];
  float* out = (float*)d_out;

  float* hbuf = (float*)d_ws;   // [NB, NT, HH] fp32 = 52.4 MB

  lstm_pipe1<<<NB, 512, 0, stream>>>(z, Wih0, Whh0, b0, hbuf);
  lstm_pipe100<<<NB, 1024, 0, stream>>>(hbuf, Wih1, Whh1, b1, hbuf);
  lstm_pipe100<<<NB, 1024, 0, stream>>>(hbuf, Wih2, Whh2, b2, hbuf);
  proj_kernel<<<(NB * NT + 255) / 256, 256, 0, stream>>>(hbuf, Wp, bp, out);
}

// Round 3
// 3027.148 us; speedup vs baseline: 2.9744x; 1.1559x over previous
//
#include <hip/hip_runtime.h>
#include <cstdint>
#include <cstddef>

// LSTM_Generator: 3-layer LSTM (H=100) + tanh projection. B=512, T=512, fp32.
//
// R2: kill the register spill. R1 counters showed VGPR_Count=64 -> compiler
// spilled w[100] (launch_bounds only sets MIN waves/EU; allocator targeted 8
// waves/SIMD). Fix: amdgpu_waves_per_eu(min,max) pins occupancy so the
// allocator gets the full budget:
//   layers 1/2: 512 thr, waves_per_eu(2,2) -> 256 VGPR budget; each gate
//               thread holds whh[100]+wih[100] (~220 regs). Wave 7 prefetches
//               x(t+1) -> LDS double buffer.
//   layer 0:    512 thr, waves_per_eu(4,4) -> 128 VGPR budget (~115 needed),
//               2 blocks/CU -> all 512 batch rows resident in one round.
// Unit-major quad map r=4u+g; gate exchange via ds_swizzle quad broadcast;
// ONE barrier per step.

#define HH 100   // hidden
#define G4 400   // 4*H
#define NB 512   // batch
#define NT 512   // timesteps

__device__ __forceinline__ float sigm(float x) {
  return 1.0f / (1.0f + __expf(-x));
}
__device__ __forceinline__ float tanh_(float x) {
  return 1.0f - 2.0f / (__expf(2.0f * x) + 1.0f);
}
// quad broadcasts: every lane of a quad gets lane (quad|k)'s value
__device__ __forceinline__ float qb1(float v) {
  return __int_as_float(__builtin_amdgcn_ds_swizzle(__float_as_int(v), 0x8055));
}
__device__ __forceinline__ float qb2(float v) {
  return __int_as_float(__builtin_amdgcn_ds_swizzle(__float_as_int(v), 0x80AA));
}
__device__ __forceinline__ float qb3(float v) {
  return __int_as_float(__builtin_amdgcn_ds_swizzle(__float_as_int(v), 0x80FF));
}

// -------- layers 1,2: K=100, both weight rows in VGPRs --------
__global__ __attribute__((amdgpu_flat_work_group_size(512, 512),
                          amdgpu_waves_per_eu(2, 2)))
void lstm_layer12(
    const float* x,                   // [NB, NT, HH]  (aliases hseq: in-place)
    const float* __restrict__ Wih,    // [G4, HH]
    const float* __restrict__ Whh,    // [G4, HH]
    const float* __restrict__ bias,   // [G4]
    float* hseq)                      // [NB, NT, HH]
{
  const int b = blockIdx.x;
  const int tid = threadIdx.x;

  __shared__ __align__(16) float h_dbuf[2][HH];
  __shared__ __align__(16) float x_dbuf[2][HH];

  const bool isG = tid < G4;
  const int u = tid >> 2, g = tid & 3;
  const int row = g * HH + u;

  float whh[HH], wih[HH];
  float bb = 0.0f, c = 0.0f;
  if (isG) {
    const float4* wh4 = reinterpret_cast<const float4*>(Whh + (size_t)row * HH);
    const float4* wi4 = reinterpret_cast<const float4*>(Wih + (size_t)row * HH);
#pragma unroll
    for (int k = 0; k < HH / 4; ++k) {
      float4 a = wh4[k];
      whh[4 * k] = a.x; whh[4 * k + 1] = a.y; whh[4 * k + 2] = a.z; whh[4 * k + 3] = a.w;
      float4 bq = wi4[k];
      wih[4 * k] = bq.x; wih[4 * k + 1] = bq.y; wih[4 * k + 2] = bq.z; wih[4 * k + 3] = bq.w;
    }
    bb = bias[row];
  }
  if (tid < HH) h_dbuf[0][tid] = 0.0f;

  const float* xb = x + (size_t)b * NT * HH;
  float* hb = hseq + (size_t)b * NT * HH;

  // wave 7 lanes 0..24: x prefetchers (float4 granularity)
  const unsigned pf = (unsigned)(tid - 448);
  if (pf < 25u) {
    reinterpret_cast<float4*>(x_dbuf[0])[pf] =
        reinterpret_cast<const float4*>(xb)[pf];
  }
  __syncthreads();

  for (int t = 0; t < NT; ++t) {
    const int cur = t & 1, nxt = cur ^ 1;

    // prefetch x(t+1) -> x_dbuf[nxt]; vmcnt drain before s_barrier orders
    // this read ahead of step t+1's in-place write of row t+1.
    if (pf < 25u) {
      int tt = (t + 1 < NT) ? t + 1 : NT - 1;
      reinterpret_cast<float4*>(x_dbuf[nxt])[pf] =
          reinterpret_cast<const float4*>(xb + (size_t)tt * HH)[pf];
    }

    if (isG) {
      float a0 = 0.f, a1 = 0.f, a2 = 0.f, a3 = 0.f;
      const float4* x4 = reinterpret_cast<const float4*>(x_dbuf[cur]);
      const float4* h4 = reinterpret_cast<const float4*>(h_dbuf[cur]);
#pragma unroll
      for (int k = 0; k < HH / 4; ++k) {
        float4 v = x4[k];
        a0 += v.x * wih[4 * k];     a1 += v.y * wih[4 * k + 1];
        a2 += v.z * wih[4 * k + 2]; a3 += v.w * wih[4 * k + 3];
      }
#pragma unroll
      for (int k = 0; k < HH / 4; ++k) {
        float4 v = h4[k];
        a0 += v.x * whh[4 * k];     a1 += v.y * whh[4 * k + 1];
        a2 += v.z * whh[4 * k + 2]; a3 += v.w * whh[4 * k + 3];
      }
      float acc = bb + ((a0 + a1) + (a2 + a3));
      float act = (g == 2) ? tanh_(acc) : sigm(acc);
      float fv = qb1(act);
      float gv = qb2(act);
      float ov = qb3(act);
      if (g == 0) {                 // lane 4u owns unit u's c,h
        c = fv * c + act * gv;
        float hv = ov * tanh_(c);
        h_dbuf[nxt][u] = hv;
        hb[(size_t)t * HH + u] = hv;
      }
    }
    __syncthreads();
  }
}

// -------- layer 0: K=1 scalar input --------
__global__ __attribute__((amdgpu_flat_work_group_size(512, 512),
                          amdgpu_waves_per_eu(4, 4)))
void lstm_layer0(
    const float* __restrict__ z,      // [NB, NT, 1]
    const float* __restrict__ Wih,    // [G4, 1]
    const float* __restrict__ Whh,    // [G4, HH]
    const float* __restrict__ bias,   // [G4]
    float* __restrict__ hseq)         // [NB, NT, HH]
{
  const int b = blockIdx.x;
  const int tid = threadIdx.x;

  __shared__ __align__(16) float h_dbuf[2][HH];

  const bool isG = tid < G4;
  const int u = tid >> 2, g = tid & 3;
  const int row = g * HH + u;

  float w[HH];
  float w0 = 0.f, bb = 0.f, c = 0.f;
  if (isG) {
    const float4* w4 = reinterpret_cast<const float4*>(Whh + (size_t)row * HH);
#pragma unroll
    for (int k = 0; k < HH / 4; ++k) {
      float4 v = w4[k];
      w[4 * k] = v.x; w[4 * k + 1] = v.y; w[4 * k + 2] = v.z; w[4 * k + 3] = v.w;
    }
    w0 = Wih[row];
    bb = bias[row];
  }
  if (tid < HH) h_dbuf[0][tid] = 0.0f;

  const float* zb = z + (size_t)b * NT;
  float* hb = hseq + (size_t)b * NT * HH;

  float zc = zb[0];
  __syncthreads();

  for (int t = 0; t < NT; ++t) {
    const int cur = t & 1, nxt = cur ^ 1;
    float zn = (t + 1 < NT) ? zb[t + 1] : 0.f;  // issue early

    if (isG) {
      float a0 = 0.f, a1 = 0.f, a2 = 0.f, a3 = 0.f;
      const float4* h4 = reinterpret_cast<const float4*>(h_dbuf[cur]);
#pragma unroll
      for (int k = 0; k < HH / 4; ++k) {
        float4 v = h4[k];
        a0 += v.x * w[4 * k];     a1 += v.y * w[4 * k + 1];
        a2 += v.z * w[4 * k + 2]; a3 += v.w * w[4 * k + 3];
      }
      float acc = bb + w0 * zc + ((a0 + a1) + (a2 + a3));
      float act = (g == 2) ? tanh_(acc) : sigm(acc);
      float fv = qb1(act);
      float gv = qb2(act);
      float ov = qb3(act);
      if (g == 0) {
        c = fv * c + act * gv;
        float hv = ov * tanh_(c);
        h_dbuf[nxt][u] = hv;
        hb[(size_t)t * HH + u] = hv;
      }
    }
    zc = zn;
    __syncthreads();
  }
}

// -------- projection --------
__global__ __launch_bounds__(256) void proj_kernel(
    const float* __restrict__ hseq,  // [NB*NT, HH]
    const float* __restrict__ Wp,    // [1, HH]
    const float* __restrict__ bp,    // [1]
    float* __restrict__ out)         // [NB*NT]
{
  int idx = blockIdx.x * blockDim.x + threadIdx.x;
  if (idx >= NB * NT) return;
  const float4* h4 = reinterpret_cast<const float4*>(hseq + (size_t)idx * HH);
  const float4* w4 = reinterpret_cast<const float4*>(Wp);
  float a0 = 0.f, a1 = 0.f, a2 = 0.f, a3 = 0.f;
#pragma unroll
  for (int k = 0; k < HH / 4; ++k) {
    float4 h = h4[k];
    float4 w = w4[k];
    a0 += h.x * w.x; a1 += h.y * w.y; a2 += h.z * w.z; a3 += h.w * w.w;
  }
  out[idx] = tanh_(((a0 + a1) + (a2 + a3)) + bp[0]);
}

extern "C" void kernel_launch(void* const* d_in, const int* in_sizes, int n_in,
                              void* d_out, int out_size, void* d_ws, size_t ws_size,
                              hipStream_t stream) {
  const float* z    = (const float*)d_in[0];
  const float* Wih0 = (const float*)d_in[1];
  const float* Whh0 = (const float*)d_in[2];
  const float* b0   = (const float*)d_in[3];
  const float* Wih1 = (const float*)d_in[4];
  const float* Whh1 = (const float*)d_in[5];
  const float* b1   = (const float*)d_in[6];
  const float* Wih2 = (const float*)d_in[7];
  const float* Whh2 = (const float*)d_in[8];
  const float* b2   = (const float*)d_in[9];
  const float* Wp   = (const float*)d_in[10];
  const float* bp   = (const float*)d_in[11];
  float* out = (float*)d_out;

  float* hbuf = (float*)d_ws;   // [NB, NT, HH] fp32 = 52.4 MB

  lstm_layer0<<<NB, 512, 0, stream>>>(z, Wih0, Whh0, b0, hbuf);
  lstm_layer12<<<NB, 512, 0, stream>>>(hbuf, Wih1, Whh1, b1, hbuf);
  lstm_layer12<<<NB, 512, 0, stream>>>(hbuf, Wih2, Whh2, b2, hbuf);
  proj_kernel<<<(NB * NT + 255) / 256, 256, 0, stream>>>(hbuf, Wp, bp, out);
}